// Round 1
// baseline (116.290 us; speedup 1.0000x reference)
//
#include <hip/hip_runtime.h>
#include <cstdint>

#define E_EDGES 400000
#define N_NODES 25000
#define GROUPS  (E_EDGES/16)   // 25000

typedef float f32x4 __attribute__((ext_vector_type(4)));
typedef __bf16 bf16x8 __attribute__((ext_vector_type(8)));

static __device__ __forceinline__ float bf2f(uint32_t u) {
    union { uint32_t u; float f; } v; v.u = u << 16; return v.f;
}
static __device__ __forceinline__ ushort f2bf(float f) {
    union { __bf16 b; ushort u; } c; c.b = (__bf16)f; return c.u;
}

// ---------------------------------------------------------------------------
// K_pre: pack W2 (plus a 17th K-tile holding b2) into bf16 MFMA-fragment order
// layout [kt:17][nt:2][kg:4][ln:16][j:8]  (17408 ushorts = 34816 B)
// value: kt<16 -> W2[m=kg*8+j][kt*32 + nt*16 + ln] ; kt==16 -> b2 tile (zero-padded)
// ---------------------------------------------------------------------------
__global__ void k_pack(const float* __restrict__ W2, const float* __restrict__ b2,
                       ushort* __restrict__ packed) {
    int t = blockIdx.x * 256 + threadIdx.x;
    if (t >= 17 * 2 * 4 * 16 * 8) return;
    int j  = t & 7;
    int ln = (t >> 3) & 15;
    int kg = (t >> 7) & 3;
    int nt = (t >> 9) & 1;
    int kt = t >> 10;
    int kap = kg * 8 + j;          // within-tile K index
    float v = 0.0f;
    if (kt < 16)       v = W2[kap * 512 + kt * 32 + nt * 16 + ln];
    else if (kap < 16) v = b2[kap * 32 + nt * 16 + ln];
    packed[t] = f2bf(v);
}

// ---------------------------------------------------------------------------
// K1: per-edge MLP hidden layer h = relu(ea @ W1 + b1), stored bf16 [E][32];
// also count edges per dst node.
// ---------------------------------------------------------------------------
__global__ void __launch_bounds__(256) k_h(const float* __restrict__ ea,
                                           const float* __restrict__ W1,
                                           const float* __restrict__ b1,
                                           const int* __restrict__ ei,
                                           ushort* __restrict__ hbuf,
                                           float* __restrict__ cnt) {
    int e = blockIdx.x * 256 + threadIdx.x;
    if (e >= E_EDGES) return;
    const f32x4* ap = (const f32x4*)(ea + (size_t)e * 8);
    f32x4 a0 = ap[0], a1 = ap[1];
    float av[8] = {a0[0], a0[1], a0[2], a0[3], a1[0], a1[1], a1[2], a1[3]};
    float hv[32];
#pragma unroll
    for (int m = 0; m < 32; ++m) {
        float s = b1[m];
#pragma unroll
        for (int k = 0; k < 8; ++k) s += av[k] * W1[k * 32 + m];
        hv[m] = fmaxf(s, 0.0f);
    }
    uint w[16];
#pragma unroll
    for (int q = 0; q < 16; ++q)
        w[q] = (uint)f2bf(hv[2 * q]) | ((uint)f2bf(hv[2 * q + 1]) << 16);
    uint4* hp = (uint4*)(hbuf + (size_t)e * 32);
    hp[0] = make_uint4(w[0],  w[1],  w[2],  w[3]);
    hp[1] = make_uint4(w[4],  w[5],  w[6],  w[7]);
    hp[2] = make_uint4(w[8],  w[9],  w[10], w[11]);
    hp[3] = make_uint4(w[12], w[13], w[14], w[15]);
    atomicAdd(&cnt[ei[E_EDGES + e]], 1.0f);
}

// ---------------------------------------------------------------------------
// K2: fused edge GEMM.  msg[16e x 32o] = A'[16e x 544] @ W2'[544 x 32]
// A'[e,(kt,m)] = x[src_e,kt]*h[e,m] built in registers; 17th tile folds b2.
// One wave per 16-edge group; 34 MFMAs per group; atomic scatter to agg.
// ---------------------------------------------------------------------------
__global__ void __launch_bounds__(256) k_edge(const ushort* __restrict__ hbuf,
                                              const float* __restrict__ x,
                                              const int* __restrict__ ei,
                                              const ushort* __restrict__ packed,
                                              float* __restrict__ agg) {
    __shared__ alignas(16) ushort w2l[17408];
    {
        const uint4* s = (const uint4*)packed;
        uint4* d = (uint4*)w2l;
        for (int i = threadIdx.x; i < 2176; i += 256) d[i] = s[i];
    }
    __syncthreads();

    const int lane = threadIdx.x & 63;
    const int ln = lane & 15;       // A row (edge in group) / B col (output)
    const int kg = lane >> 4;       // k-group
    const int gw = blockIdx.x * 4 + (threadIdx.x >> 6);

    for (int g = gw; g < GROUPS; g += gridDim.x * 4) {
        const int g16 = g * 16;
        const int e = g16 + ln;
        const int srcn = ei[e];

        // x row of my edge (16 f32)
        const f32x4* xp = (const f32x4*)(x + (size_t)srcn * 16);
        f32x4 xq0 = xp[0], xq1 = xp[1], xq2 = xp[2], xq3 = xp[3];
        float xr[16];
        xr[0]=xq0[0]; xr[1]=xq0[1]; xr[2]=xq0[2]; xr[3]=xq0[3];
        xr[4]=xq1[0]; xr[5]=xq1[1]; xr[6]=xq1[2]; xr[7]=xq1[3];
        xr[8]=xq2[0]; xr[9]=xq2[1]; xr[10]=xq2[2]; xr[11]=xq2[3];
        xr[12]=xq3[0]; xr[13]=xq3[1]; xr[14]=xq3[2]; xr[15]=xq3[3];

        // my 8 h values (bf16 -> f32)
        const uint4 hvp = *(const uint4*)(hbuf + (size_t)e * 32 + kg * 8);
        float hf[8];
        hf[0] = bf2f(hvp.x & 0xffffu); hf[1] = bf2f(hvp.x >> 16);
        hf[2] = bf2f(hvp.y & 0xffffu); hf[3] = bf2f(hvp.y >> 16);
        hf[4] = bf2f(hvp.z & 0xffffu); hf[5] = bf2f(hvp.z >> 16);
        hf[6] = bf2f(hvp.w & 0xffffu); hf[7] = bf2f(hvp.w >> 16);

        f32x4 acc0 = {0.f, 0.f, 0.f, 0.f};
        f32x4 acc1 = {0.f, 0.f, 0.f, 0.f};

#pragma unroll
        for (int kt = 0; kt < 16; ++kt) {
            const float xv = xr[kt];
            bf16x8 a;
#pragma unroll
            for (int j = 0; j < 8; ++j) a[j] = (__bf16)(xv * hf[j]);
            const bf16x8 b0 = *(const bf16x8*)(&w2l[(kt * 2 + 0) * 512 + lane * 8]);
            const bf16x8 b1v = *(const bf16x8*)(&w2l[(kt * 2 + 1) * 512 + lane * 8]);
            acc0 = __builtin_amdgcn_mfma_f32_16x16x32_bf16(a, b0,  acc0, 0, 0, 0);
            acc1 = __builtin_amdgcn_mfma_f32_16x16x32_bf16(a, b1v, acc1, 0, 0, 0);
        }
        // 17th tile: A = x (zero-padded beyond i=16), B = packed b2 tile
        {
            float l0 = (kg == 0) ? xq0[0] : ((kg == 1) ? xq2[0] : 0.f);
            float l1 = (kg == 0) ? xq0[1] : ((kg == 1) ? xq2[1] : 0.f);
            float l2 = (kg == 0) ? xq0[2] : ((kg == 1) ? xq2[2] : 0.f);
            float l3 = (kg == 0) ? xq0[3] : ((kg == 1) ? xq2[3] : 0.f);
            float h0 = (kg == 0) ? xq1[0] : ((kg == 1) ? xq3[0] : 0.f);
            float h1 = (kg == 0) ? xq1[1] : ((kg == 1) ? xq3[1] : 0.f);
            float h2 = (kg == 0) ? xq1[2] : ((kg == 1) ? xq3[2] : 0.f);
            float h3 = (kg == 0) ? xq1[3] : ((kg == 1) ? xq3[3] : 0.f);
            bf16x8 a;
            a[0]=(__bf16)l0; a[1]=(__bf16)l1; a[2]=(__bf16)l2; a[3]=(__bf16)l3;
            a[4]=(__bf16)h0; a[5]=(__bf16)h1; a[6]=(__bf16)h2; a[7]=(__bf16)h3;
            const bf16x8 b0 = *(const bf16x8*)(&w2l[(16 * 2 + 0) * 512 + lane * 8]);
            const bf16x8 b1v = *(const bf16x8*)(&w2l[(16 * 2 + 1) * 512 + lane * 8]);
            acc0 = __builtin_amdgcn_mfma_f32_16x16x32_bf16(a, b0,  acc0, 0, 0, 0);
            acc1 = __builtin_amdgcn_mfma_f32_16x16x32_bf16(a, b1v, acc1, 0, 0, 0);
        }

        // scatter: C row r=(kg*4+j) is edge g16+r, col = nt*16+ln
        const int d0 = ei[E_EDGES + g16 + kg * 4 + 0];
        const int d1 = ei[E_EDGES + g16 + kg * 4 + 1];
        const int d2 = ei[E_EDGES + g16 + kg * 4 + 2];
        const int d3 = ei[E_EDGES + g16 + kg * 4 + 3];
        atomicAdd(&agg[d0 * 32 + ln],      acc0[0]);
        atomicAdd(&agg[d1 * 32 + ln],      acc0[1]);
        atomicAdd(&agg[d2 * 32 + ln],      acc0[2]);
        atomicAdd(&agg[d3 * 32 + ln],      acc0[3]);
        atomicAdd(&agg[d0 * 32 + 16 + ln], acc1[0]);
        atomicAdd(&agg[d1 * 32 + 16 + ln], acc1[1]);
        atomicAdd(&agg[d2 * 32 + 16 + ln], acc1[2]);
        atomicAdd(&agg[d3 * 32 + 16 + ln], acc1[3]);
    }
}

// ---------------------------------------------------------------------------
// K3a: a[n,h] = relu(agg/max(cnt,1) + x@root + bias)
// ---------------------------------------------------------------------------
__global__ void __launch_bounds__(256) k_node_a(const float* __restrict__ agg,
                                                const float* __restrict__ cnt,
                                                const float* __restrict__ x,
                                                const float* __restrict__ root,
                                                const float* __restrict__ bias,
                                                float* __restrict__ abuf) {
    int t = blockIdx.x * 256 + threadIdx.x;
    if (t >= N_NODES * 32) return;
    int n = t >> 5, h = t & 31;
    float s = agg[t] / fmaxf(cnt[n], 1.0f) + bias[h];
#pragma unroll
    for (int i = 0; i < 16; ++i) s += x[n * 16 + i] * root[i * 32 + h];
    abuf[t] = fmaxf(s, 0.0f);
}

// ---------------------------------------------------------------------------
// K3b: out[n,j] = a[n,:] @ Wlin + blin
// ---------------------------------------------------------------------------
__global__ void __launch_bounds__(256) k_node_out(const float* __restrict__ abuf,
                                                  const float* __restrict__ Wlin,
                                                  const float* __restrict__ blin,
                                                  float* __restrict__ out) {
    int t = blockIdx.x * 256 + threadIdx.x;
    if (t >= N_NODES * 16) return;
    int n = t >> 4, j = t & 15;
    float s = blin[j];
#pragma unroll
    for (int h = 0; h < 32; ++h) s += abuf[n * 32 + h] * Wlin[h * 16 + j];
    out[t] = s;
}

// ---------------------------------------------------------------------------
extern "C" void kernel_launch(void* const* d_in, const int* in_sizes, int n_in,
                              void* d_out, int out_size, void* d_ws, size_t ws_size,
                              hipStream_t stream) {
    const float* x    = (const float*)d_in[0];
    const float* ea   = (const float*)d_in[1];
    const float* W1   = (const float*)d_in[2];
    const float* b1   = (const float*)d_in[3];
    const float* W2   = (const float*)d_in[4];
    const float* b2   = (const float*)d_in[5];
    const float* root = (const float*)d_in[6];
    const float* bias = (const float*)d_in[7];
    const float* Wlin = (const float*)d_in[8];
    const float* blin = (const float*)d_in[9];
    const int*   ei   = (const int*)d_in[10];
    float* out = (float*)d_out;

    char* ws = (char*)d_ws;
    float*  agg    = (float*)(ws + 0);           // 3,200,000 B
    float*  cnt    = (float*)(ws + 3200000);     //   100,000 B
    ushort* hbuf   = (ushort*)(ws + 3300000);    // 25,600,000 B
    ushort* packed = (ushort*)(ws + 28900000);   //     34,816 B
    float*  abuf   = (float*)(ws + 28934816);    // 3,200,000 B

    hipMemsetAsync(d_ws, 0, 3300000, stream);    // agg + cnt

    k_pack<<<68, 256, 0, stream>>>(W2, b2, packed);
    k_h<<<(E_EDGES + 255) / 256, 256, 0, stream>>>(ea, W1, b1, ei, hbuf, cnt);
    k_edge<<<1024, 256, 0, stream>>>(hbuf, x, ei, packed, agg);
    k_node_a<<<(N_NODES * 32 + 255) / 256, 256, 0, stream>>>(agg, cnt, x, root, bias, abuf);
    k_node_out<<<(N_NODES * 16 + 255) / 256, 256, 0, stream>>>(abuf, Wlin, blin, out);
}